// Round 3
// baseline (12107.693 us; speedup 1.0000x reference)
//
#include <hip/hip_runtime.h>
#include <cstdint>
#include <cstddef>

// DecoderLSTM: 2-layer LSTM (B=512,H=512,T=128) + 3-layer MLP head.
// bf16 MFMA; A-operand bf16 hi+lo (K doubled) for accuracy; fp32 cell state.
// Round 3: persistent LSTM kernel — one dispatch for all 256 layer-steps,
// grid barrier via device-scope atomics, c-state + h0 carried in VGPRs.

using u16 = unsigned short;
typedef __attribute__((ext_vector_type(8))) short bf16x8;
typedef __attribute__((ext_vector_type(4))) float f32x4;

__device__ __forceinline__ u16 f2bf(float f) {
    union { float f; uint32_t u; } v; v.f = f;
    uint32_t u = v.u;
    uint32_t r = (u + 0x7fffu + ((u >> 16) & 1u)) >> 16;
    return (u16)r;
}
__device__ __forceinline__ float bf2f(u16 h) {
    union { uint32_t u; float f; } v; v.u = ((uint32_t)h) << 16;
    return v.f;
}
__device__ __forceinline__ float tanh_fast(float v) {
    float a = fabsf(v);
    float t = __expf(-2.f * a);
    float r = (1.f - t) / (1.f + t);
    return copysignf(r, v);
}
__device__ __forceinline__ float sigmoid_fast(float v) {
    return 1.f / (1.f + __expf(-v));
}

__device__ __forceinline__ void gl_lds16(const u16* g, char* l) {
    __builtin_amdgcn_global_load_lds((const __attribute__((address_space(1))) char*)(const char*)g,
                                     (__attribute__((address_space(3))) char*)l, 16, 0, 0);
}

// Swizzled LDS read: tile [64 rows][64 bf16] linear (128B rows = 8 x 16B units),
// unit u' holds global col-unit u'^(row&7).
__device__ __forceinline__ bf16x8 lds_read_sw(const u16* tile, int row, int cu) {
    int unit = (row << 3) | (cu ^ (row & 7));
    return *(const bf16x8*)&tile[unit << 3];
}

// ---------------------------------------------------------------- prepack ----
__global__ __launch_bounds__(256) void prepack(
    const float* __restrict__ W_ih, const float* __restrict__ W_hh,
    const float* __restrict__ b_ih, const float* __restrict__ b_hh,
    const float* __restrict__ fc1w, const float* __restrict__ fc2w, const float* __restrict__ fc3w,
    u16* __restrict__ Bpack, float* __restrict__ bsumv, u16* __restrict__ fcw)
{
    int stride = gridDim.x * blockDim.x;
    int tid0 = blockIdx.x * blockDim.x + threadIdx.x;
    for (int idx = tid0; idx < 2 * 2048 * 1024; idx += stride) {
        int l = idx >> 21;
        int rem = idx & ((1 << 21) - 1);
        int np = rem >> 10;
        int k = rem & 1023;
        int n = (np & 3) * 512 + (np >> 2);
        float v = (k < 512) ? W_ih[((size_t)l * 2048 + n) * 512 + k]
                            : W_hh[((size_t)l * 2048 + n) * 512 + (k - 512)];
        Bpack[idx] = f2bf(v);
    }
    for (int idx = tid0; idx < 2 * 2048; idx += stride) {
        int l = idx >> 11;
        int np = idx & 2047;
        int n = (np & 3) * 512 + (np >> 2);
        bsumv[idx] = b_ih[l * 2048 + n] + b_hh[l * 2048 + n];
    }
    for (int idx = tid0; idx < 3 * 512 * 512; idx += stride) {
        const float* w = idx < 262144 ? fc1w : (idx < 524288 ? fc2w : fc3w);
        fcw[idx] = f2bf(w[idx & 262143]);
    }
}

// A buffers: [512][2048] bf16: [0:512)=x/hsum hi, [512:1024)=h hi, [1024:1536)=x lo, [1536:2048)=h lo
__global__ __launch_bounds__(256) void initbufs(
    const float* __restrict__ x, u16* __restrict__ A0_0, u16* __restrict__ A1_0,
    unsigned* bar_cnt, unsigned* bar_flag)
{
    int stride = gridDim.x * blockDim.x;
    int tid0 = blockIdx.x * blockDim.x + threadIdx.x;
    if (tid0 == 0) { *bar_cnt = 0u; *bar_flag = 0u; }
    for (int idx = tid0; idx < 512 * 512; idx += stride) {
        int row = idx >> 9, col = idx & 511;
        float xv = x[idx];
        u16 hi = f2bf(xv);
        float lo = xv - bf2f(hi);
        size_t b = (size_t)row * 2048;
        A0_0[b + col] = hi;
        A0_0[b + 1024 + col] = f2bf(lo);
        A0_0[b + 512 + col] = 0;
        A0_0[b + 1536 + col] = 0;
        A1_0[b + 512 + col] = 0;
        A1_0[b + 1536 + col] = 0;
    }
}

// ------------------------------------------------------- persistent LSTM -----
// 256 blocks x 256 thr, 1/CU, co-resident. Each block owns (rg, nb) forever:
// rows rg*64..+64, n'-cols nb*64..+64 (= 16 h-cols). 256 sub-steps, grid barrier between.
__global__ __launch_bounds__(256) void lstm_persist(
    u16* __restrict__ A00, u16* __restrict__ A01,
    u16* __restrict__ A10, u16* __restrict__ A11,
    const u16* __restrict__ Bp, const float* __restrict__ bsumv,
    u16* __restrict__ seqb, unsigned* bar_cnt, unsigned* bar_flag)
{
    __shared__ char smem[49152];  // AH0=0 AL0=8K AH1=16K AL1=24K B0=32K B1=40K

    const int id = blockIdx.x;
    const int xcd = id & 7, slot = id >> 3;
    const int nb = xcd * 4 + (slot & 3);   // 0..31
    const int rg = slot >> 2;              // 0..7
    const int n0 = nb * 64;
    const int row0 = rg * 64;

    const int tid = threadIdx.x;
    const int lane = tid & 63, wid = tid >> 6;
    const int wm = (wid >> 1) * 32, wn = (wid & 1) * 32;
    const int fm = lane & 15, q = lane >> 4;

    // staging: wave w stages 16B-units [w*128, w*128+128); global src pre-swizzled
    const int s0 = wid * 128 + lane, s1 = s0 + 64;
    const int r0s = s0 >> 3, c0s = ((s0 & 7) ^ (r0s & 7)) << 3;
    const int r1s = s1 >> 3, c1s = ((s1 & 7) ^ (r1s & 7)) << 3;
    const size_t aO0 = (size_t)(row0 + r0s) * 2048 + c0s;
    const size_t aO1 = (size_t)(row0 + r1s) * 2048 + c1s;
    const size_t bO0 = (size_t)(n0 + r0s) * 1024 + c0s;
    const size_t bO1 = (size_t)(n0 + r1s) * 1024 + c1s;
    const int d0 = wid * 2048, d1 = d0 + 1024;

    u16* Ab0[2] = { A00, A01 };
    u16* Ab1[2] = { A10, A11 };

    float creg[2][4] = { {0.f,0.f,0.f,0.f}, {0.f,0.f,0.f,0.f} };
    float h0f[4] = { 0.f, 0.f, 0.f, 0.f };

    for (int ss = 0; ss < 256; ++ss) {
        const int t = ss >> 1, layer = ss & 1;
        const int cur = t & 1, nxt = cur ^ 1;
        const u16* Ain = layer ? Ab1[cur] : Ab0[cur];
        const u16* Bl = Bp + (size_t)layer * (2048 * 1024);
        const float* bs = bsumv + layer * 2048;

        f32x4 acc[2][2];
        acc[0][0] = (f32x4)0.f; acc[0][1] = (f32x4)0.f;
        acc[1][0] = (f32x4)0.f; acc[1][1] = (f32x4)0.f;

        auto stage = [&](int buf, int k0) {
            char* th = smem + buf * 16384;
            char* tl = th + 8192;
            char* tb = smem + 32768 + buf * 8192;
            gl_lds16(Ain + aO0 + k0, th + d0);
            gl_lds16(Ain + aO1 + k0, th + d1);
            gl_lds16(Ain + aO0 + 1024 + k0, tl + d0);
            gl_lds16(Ain + aO1 + 1024 + k0, tl + d1);
            gl_lds16(Bl + bO0 + k0, tb + d0);
            gl_lds16(Bl + bO1 + k0, tb + d1);
        };

        stage(0, 0);
        __syncthreads();

        for (int c = 0; c < 16; ++c) {
            const int curb = c & 1;
            if (c < 15) stage(curb ^ 1, (c + 1) * 64);

            const u16* sAhi = (const u16*)(smem + curb * 16384);
            const u16* sAlo = (const u16*)(smem + curb * 16384 + 8192);
            const u16* sB   = (const u16*)(smem + 32768 + curb * 8192);

#pragma unroll
            for (int kf = 0; kf < 2; ++kf) {
                const int cu = kf * 4 + q;
                bf16x8 b0 = lds_read_sw(sB, wn + fm, cu);
                bf16x8 b1 = lds_read_sw(sB, wn + 16 + fm, cu);
                bf16x8 ah0 = lds_read_sw(sAhi, wm + fm, cu);
                bf16x8 ah1 = lds_read_sw(sAhi, wm + 16 + fm, cu);
                bf16x8 al0 = lds_read_sw(sAlo, wm + fm, cu);
                bf16x8 al1 = lds_read_sw(sAlo, wm + 16 + fm, cu);
                acc[0][0] = __builtin_amdgcn_mfma_f32_16x16x32_bf16(ah0, b0, acc[0][0], 0, 0, 0);
                acc[0][1] = __builtin_amdgcn_mfma_f32_16x16x32_bf16(ah0, b1, acc[0][1], 0, 0, 0);
                acc[1][0] = __builtin_amdgcn_mfma_f32_16x16x32_bf16(ah1, b0, acc[1][0], 0, 0, 0);
                acc[1][1] = __builtin_amdgcn_mfma_f32_16x16x32_bf16(ah1, b1, acc[1][1], 0, 0, 0);
                acc[0][0] = __builtin_amdgcn_mfma_f32_16x16x32_bf16(al0, b0, acc[0][0], 0, 0, 0);
                acc[0][1] = __builtin_amdgcn_mfma_f32_16x16x32_bf16(al0, b1, acc[0][1], 0, 0, 0);
                acc[1][0] = __builtin_amdgcn_mfma_f32_16x16x32_bf16(al1, b0, acc[1][0], 0, 0, 0);
                acc[1][1] = __builtin_amdgcn_mfma_f32_16x16x32_bf16(al1, b1, acc[1][1], 0, 0, 0);
            }
            __syncthreads();
        }

        // ---- epilogue: acc -> sG (fp32 [64][68], fits in 0..17.4KB) -> LSTM cell
        float* sG = (float*)smem;
#pragma unroll
        for (int m = 0; m < 2; ++m)
#pragma unroll
            for (int n = 0; n < 2; ++n)
#pragma unroll
                for (int r = 0; r < 4; ++r) {
                    int row = wm + m * 16 + q * 4 + r;
                    int col = wn + n * 16 + fm;
                    sG[row * 68 + col] = acc[m][n][r];
                }
        __syncthreads();

#pragma unroll
        for (int j = 0; j < 4; ++j) {
            int cell = tid + j * 256;         // 64 rows x 16 h-cols
            int row = cell >> 4, hc = cell & 15;
            const float4 g4 = *(const float4*)&sG[row * 68 + hc * 4];
            const float4 b4 = *(const float4*)&bs[n0 + hc * 4];
            float gi = g4.x + b4.x, gf = g4.y + b4.y, gg = g4.z + b4.z, go = g4.w + b4.w;
            float c_old = creg[layer][j];
            float is = sigmoid_fast(gi);
            float fs = sigmoid_fast(gf);
            float os = sigmoid_fast(go);
            float gt = tanh_fast(gg);
            float cn = fs * c_old + is * gt;
            float hn = os * tanh_fast(cn);
            creg[layer][j] = cn;
            u16 hh = f2bf(hn);
            float hlo = hn - bf2f(hh);
            u16 hl = f2bf(hlo);
            int grow = row0 + row;
            int ghc = (n0 >> 2) + hc;
            size_t ab = (size_t)grow * 2048;
            if (layer == 0) {
                u16* A1c = Ab1[cur];
                A1c[ab + ghc] = hh;  A1c[ab + 1024 + ghc] = hl;
                u16* A0n = Ab0[nxt];
                A0n[ab + 512 + ghc] = hh;  A0n[ab + 1536 + ghc] = hl;
                h0f[j] = hn;
            } else {
                u16* A1n = Ab1[nxt];
                A1n[ab + 512 + ghc] = hh;  A1n[ab + 1536 + ghc] = hl;
                float hs = h0f[j] + hn;
                u16 sh = f2bf(hs);
                float sl = hs - bf2f(sh);
                u16* A0n = Ab0[nxt];
                A0n[ab + ghc] = sh;  A0n[ab + 1024 + ghc] = f2bf(sl);
                seqb[(size_t)t * 262144 + (size_t)grow * 512 + ghc] = sh;
            }
        }

        // ---- grid barrier (sense = generation counter ss)
        __builtin_amdgcn_fence(__ATOMIC_RELEASE, "agent");   // push h-writes device-wide
        __syncthreads();
        if (tid == 0) {
            unsigned old = __hip_atomic_fetch_add(bar_cnt, 1u, __ATOMIC_ACQ_REL, __HIP_MEMORY_SCOPE_AGENT);
            if (old == (unsigned)ss * 256u + 255u) {
                __hip_atomic_store(bar_flag, (unsigned)ss + 1u, __ATOMIC_RELEASE, __HIP_MEMORY_SCOPE_AGENT);
            } else {
                while (__hip_atomic_load(bar_flag, __ATOMIC_ACQUIRE, __HIP_MEMORY_SCOPE_AGENT) < (unsigned)ss + 1u) {
                    __builtin_amdgcn_s_sleep(2);
                }
            }
        }
        __syncthreads();
        __builtin_amdgcn_fence(__ATOMIC_ACQUIRE, "agent");   // invalidate stale L1/L2 lines
    }
}

// ------------------------------------------------------------------- MLP -----
template <int RELU, int FINAL>
__global__ __launch_bounds__(256) void mlp_gemm(
    const u16* __restrict__ A, const u16* __restrict__ Bw, const float* __restrict__ bias,
    u16* __restrict__ ybf, float* __restrict__ yf32)
{
    __shared__ char smem[36864];
    u16* sA = (u16*)smem;             // [64][72]
    u16* sB = (u16*)(smem + 9216);    // [128][72]

    const int tid = threadIdx.x;
    const int lane = tid & 63, wid = tid >> 6;
    const int row0 = blockIdx.y * 64;
    const int n0 = blockIdx.x * 128;
    const int wn = wid * 32;
    const int fm = lane & 15;
    const int fkbase = (lane >> 4) * 8;

    f32x4 acc[4][2];
#pragma unroll
    for (int m = 0; m < 4; ++m) { acc[m][0] = (f32x4)0.f; acc[m][1] = (f32x4)0.f; }

    for (int kk = 0; kk < 8; ++kk) {
        const int k0 = kk * 64;
        __syncthreads();
#pragma unroll
        for (int r = 0; r < 2; ++r) {
            int c = tid + r * 256;
            int row = c >> 3, cc = (c & 7) * 8;
            *(bf16x8*)&sA[row * 72 + cc] = *(const bf16x8*)&A[(size_t)(row0 + row) * 512 + k0 + cc];
        }
#pragma unroll
        for (int r = 0; r < 4; ++r) {
            int c = tid + r * 256;
            int row = c >> 3, cc = (c & 7) * 8;
            *(bf16x8*)&sB[row * 72 + cc] = *(const bf16x8*)&Bw[(size_t)(n0 + row) * 512 + k0 + cc];
        }
        __syncthreads();
#pragma unroll
        for (int kf = 0; kf < 2; ++kf) {
            const int kb = kf * 32 + fkbase;
            bf16x8 b0 = *(const bf16x8*)&sB[(wn + fm) * 72 + kb];
            bf16x8 b1 = *(const bf16x8*)&sB[(wn + 16 + fm) * 72 + kb];
#pragma unroll
            for (int m = 0; m < 4; ++m) {
                bf16x8 ah = *(const bf16x8*)&sA[(m * 16 + fm) * 72 + kb];
                acc[m][0] = __builtin_amdgcn_mfma_f32_16x16x32_bf16(ah, b0, acc[m][0], 0, 0, 0);
                acc[m][1] = __builtin_amdgcn_mfma_f32_16x16x32_bf16(ah, b1, acc[m][1], 0, 0, 0);
            }
        }
    }

    __syncthreads();
    float* sG = (float*)smem;  // [64][132]
#pragma unroll
    for (int m = 0; m < 4; ++m)
#pragma unroll
        for (int n = 0; n < 2; ++n)
#pragma unroll
            for (int r = 0; r < 4; ++r) {
                int row = m * 16 + (lane >> 4) * 4 + r;
                int col = wn + n * 16 + fm;
                sG[row * 132 + col] = acc[m][n][r];
            }
    __syncthreads();

    const int row = tid >> 2;
    const int cg = (tid & 3) * 32;
    const size_t r = (size_t)row0 + row;
#pragma unroll
    for (int c = cg; c < cg + 32; c += 4) {
        float4 g = *(const float4*)&sG[row * 132 + c];
        float4 b = *(const float4*)&bias[n0 + c];
        float v0 = g.x + b.x, v1 = g.y + b.y, v2 = g.z + b.z, v3 = g.w + b.w;
        if (RELU) {
            v0 = fmaxf(v0, 0.f); v1 = fmaxf(v1, 0.f); v2 = fmaxf(v2, 0.f); v3 = fmaxf(v3, 0.f);
        }
        if (!FINAL) {
            ushort4 p;
            p.x = f2bf(v0); p.y = f2bf(v1); p.z = f2bf(v2); p.w = f2bf(v3);
            *(ushort4*)&ybf[r * 512 + n0 + c] = p;
        } else {
            int tt = (int)(r >> 9), bb = (int)(r & 511);  // seq row r = t*512 + b
            float4 o; o.x = v0; o.y = v1; o.z = v2; o.w = v3;
            *(float4*)&yf32[((size_t)bb * 128 + tt) * 512 + n0 + c] = o;
        }
    }
}

// ---------------------------------------------------------------- launch -----
extern "C" void kernel_launch(void* const* d_in, const int* in_sizes, int n_in,
                              void* d_out, int out_size, void* d_ws, size_t ws_size,
                              hipStream_t stream) {
    const float* x    = (const float*)d_in[0];
    const float* W_ih = (const float*)d_in[1];
    const float* W_hh = (const float*)d_in[2];
    const float* b_ih = (const float*)d_in[3];
    const float* b_hh = (const float*)d_in[4];
    const float* fc1w = (const float*)d_in[5];
    const float* fc1b = (const float*)d_in[6];
    const float* fc2w = (const float*)d_in[7];
    const float* fc2b = (const float*)d_in[8];
    const float* fc3w = (const float*)d_in[9];
    const float* fc3b = (const float*)d_in[10];

    char* ws = (char*)d_ws;
    u16* Bpack = (u16*)(ws);                          // 8,388,608 B
    u16* fcw   = (u16*)(ws + 8388608);                // 1,572,864 B
    float* bsum = (float*)(ws + 9961472);             // 16,384 B
    u16* A0[2] = { (u16*)(ws + 9977856), (u16*)(ws + 9977856 + 2097152) };
    u16* A1[2] = { (u16*)(ws + 14172160), (u16*)(ws + 14172160 + 2097152) };
    unsigned* bar_cnt  = (unsigned*)(ws + 18366464);
    unsigned* bar_flag = (unsigned*)(ws + 18366464 + 128);
    u16* seqb = (u16*)(ws + 20463616);                // 67,108,864 (reused as y2)
    u16* y1   = (u16*)(ws + 87572480);                // 67,108,864
    float* out = (float*)d_out;

    prepack<<<dim3(512), dim3(256), 0, stream>>>(W_ih, W_hh, b_ih, b_hh, fc1w, fc2w, fc3w,
                                                 Bpack, bsum, fcw);
    initbufs<<<dim3(512), dim3(256), 0, stream>>>(x, A0[0], A1[0], bar_cnt, bar_flag);

    lstm_persist<<<dim3(256), dim3(256), 0, stream>>>(
        A0[0], A0[1], A1[0], A1[1], Bpack, bsum, seqb, bar_cnt, bar_flag);

    mlp_gemm<1, 0><<<dim3(4, 1024), dim3(256), 0, stream>>>(seqb, fcw, fc1b, y1, nullptr);
    mlp_gemm<1, 0><<<dim3(4, 1024), dim3(256), 0, stream>>>(y1, fcw + 512 * 512, fc2b, seqb, nullptr);
    mlp_gemm<0, 1><<<dim3(4, 1024), dim3(256), 0, stream>>>(seqb, fcw + 2 * 512 * 512, fc3b, nullptr, out);
}

// Round 4
// 2971.855 us; speedup vs baseline: 4.0741x; 4.0741x over previous
//
#include <hip/hip_runtime.h>
#include <cstdint>
#include <cstddef>

// DecoderLSTM: 2-layer LSTM (B=512,H=512,T=128) + 3-layer MLP head.
// bf16 MFMA; A-operand bf16 hi+lo (K doubled) for accuracy; fp32 cell state.
// Round 4: revert to multi-dispatch (persistent+grid-barrier killed L2 residency:
// 10.7MB HBM refetch/step). lstm_step now uses a depth-3 counted-vmcnt pipeline
// (4 LDS buffers, s_waitcnt vmcnt(12) -> s_barrier -> stage(c+3) -> consume(c));
// loads stay in flight across barriers, no vmcnt(0) drain in the main loop.

using u16 = unsigned short;
typedef __attribute__((ext_vector_type(8))) short bf16x8;
typedef __attribute__((ext_vector_type(4))) float f32x4;

__device__ __forceinline__ u16 f2bf(float f) {
    union { float f; uint32_t u; } v; v.f = f;
    uint32_t u = v.u;
    uint32_t r = (u + 0x7fffu + ((u >> 16) & 1u)) >> 16;
    return (u16)r;
}
__device__ __forceinline__ float bf2f(u16 h) {
    union { uint32_t u; float f; } v; v.u = ((uint32_t)h) << 16;
    return v.f;
}
__device__ __forceinline__ float tanh_fast(float v) {
    float a = fabsf(v);
    float t = __expf(-2.f * a);
    float r = (1.f - t) / (1.f + t);
    return copysignf(r, v);
}
__device__ __forceinline__ float sigmoid_fast(float v) {
    return 1.f / (1.f + __expf(-v));
}

__device__ __forceinline__ void gl_lds16(const u16* g, char* l) {
    __builtin_amdgcn_global_load_lds((const __attribute__((address_space(1))) char*)(const char*)g,
                                     (__attribute__((address_space(3))) char*)l, 16, 0, 0);
}

// Swizzled LDS read: tile [64 rows][64 bf16] linear (128B rows = 8 x 16B units),
// unit u' holds global col-unit u'^(row&7). (Involution: applied to global src on
// stage and to the read index here — rule "both sides or neither".)
__device__ __forceinline__ bf16x8 lds_read_sw(const u16* tile, int row, int cu) {
    int unit = (row << 3) | (cu ^ (row & 7));
    return *(const bf16x8*)&tile[unit << 3];
}

// ---------------------------------------------------------------- prepack ----
// Bpack[l][np][k], np = hcol*4 + gate (i,f,g,o), k: 0..511 = W_ih, 512..1023 = W_hh
__global__ __launch_bounds__(256) void prepack(
    const float* __restrict__ W_ih, const float* __restrict__ W_hh,
    const float* __restrict__ b_ih, const float* __restrict__ b_hh,
    const float* __restrict__ fc1w, const float* __restrict__ fc2w, const float* __restrict__ fc3w,
    u16* __restrict__ Bpack, float* __restrict__ bsumv, u16* __restrict__ fcw)
{
    int stride = gridDim.x * blockDim.x;
    int tid0 = blockIdx.x * blockDim.x + threadIdx.x;
    for (int idx = tid0; idx < 2 * 2048 * 1024; idx += stride) {
        int l = idx >> 21;
        int rem = idx & ((1 << 21) - 1);
        int np = rem >> 10;
        int k = rem & 1023;
        int n = (np & 3) * 512 + (np >> 2);
        float v = (k < 512) ? W_ih[((size_t)l * 2048 + n) * 512 + k]
                            : W_hh[((size_t)l * 2048 + n) * 512 + (k - 512)];
        Bpack[idx] = f2bf(v);
    }
    for (int idx = tid0; idx < 2 * 2048; idx += stride) {
        int l = idx >> 11;
        int np = idx & 2047;
        int n = (np & 3) * 512 + (np >> 2);
        bsumv[idx] = b_ih[l * 2048 + n] + b_hh[l * 2048 + n];
    }
    for (int idx = tid0; idx < 3 * 512 * 512; idx += stride) {
        const float* w = idx < 262144 ? fc1w : (idx < 524288 ? fc2w : fc3w);
        fcw[idx] = f2bf(w[idx & 262143]);
    }
}

// A buffers: [512][2048] bf16: [0:512)=x/hsum hi, [512:1024)=h hi, [1024:1536)=x lo, [1536:2048)=h lo
__global__ __launch_bounds__(256) void initbufs(
    const float* __restrict__ x, u16* __restrict__ A0_0, u16* __restrict__ A1_0,
    float* __restrict__ c0, float* __restrict__ c1)
{
    int stride = gridDim.x * blockDim.x;
    int tid0 = blockIdx.x * blockDim.x + threadIdx.x;
    for (int idx = tid0; idx < 512 * 512; idx += stride) {
        int row = idx >> 9, col = idx & 511;
        float xv = x[idx];
        u16 hi = f2bf(xv);
        float lo = xv - bf2f(hi);
        size_t b = (size_t)row * 2048;
        A0_0[b + col] = hi;
        A0_0[b + 1024 + col] = f2bf(lo);
        A0_0[b + 512 + col] = 0;
        A0_0[b + 1536 + col] = 0;
        A1_0[b + 512 + col] = 0;
        A1_0[b + 1536 + col] = 0;
        c0[idx] = 0.f;
        c1[idx] = 0.f;
    }
}

// --------------------------------------------------------------- lstm step ---
// 256 blocks x 256 thr (1/CU). Block: 64 rows x 64 n'-cols, K=1024 logical (x+h),
// A hi+lo. 4 waves, each a 32x32 quadrant. Depth-3 counted-vmcnt pipeline:
// 4 buffers x 24KB; per chunk: 6 global_load_lds (wave-private slices), 12
// ds_read_b128, 16 MFMA. vmcnt(12) keeps 2 chunks in flight across the barrier.
template <int IS_L1>
__global__ __launch_bounds__(256) void lstm_step(
    const u16* __restrict__ A, const u16* __restrict__ Bp, const float* __restrict__ bsumv,
    float* cbuf, u16* hdst1, int hoff1, u16* hdst2, int hoff2,
    const u16* h0src, u16* hsumdst, u16* seqdst)
{
    __shared__ char smem[98304];   // 4 bufs x (AH 8K | AL 8K | B 8K)

    const int id = blockIdx.x;
    const int xcd = id & 7, slot = id >> 3;
    const int nb = xcd * 4 + (slot & 3);   // 0..31
    const int rg = slot >> 2;              // 0..7
    const int n0 = nb * 64;
    const int row0 = rg * 64;

    const int tid = threadIdx.x;
    const int lane = tid & 63, wid = tid >> 6;
    const int wm = (wid >> 1) * 32, wn = (wid & 1) * 32;
    const int fm = lane & 15, q = lane >> 4;

    // staging: wave w stages 16B-units [w*128, w*128+128); global src pre-swizzled
    const int s0 = wid * 128 + lane, s1 = s0 + 64;
    const int r0s = s0 >> 3, c0s = ((s0 & 7) ^ (r0s & 7)) << 3;
    const int r1s = s1 >> 3, c1s = ((s1 & 7) ^ (r1s & 7)) << 3;
    const size_t aO0 = (size_t)(row0 + r0s) * 2048 + c0s;
    const size_t aO1 = (size_t)(row0 + r1s) * 2048 + c1s;
    const size_t bO0 = (size_t)(n0 + r0s) * 1024 + c0s;
    const size_t bO1 = (size_t)(n0 + r1s) * 1024 + c1s;
    const int d0 = wid * 2048, d1 = d0 + 1024;

    f32x4 acc[2][2];
    acc[0][0] = (f32x4)0.f; acc[0][1] = (f32x4)0.f;
    acc[1][0] = (f32x4)0.f; acc[1][1] = (f32x4)0.f;

    auto stage = [&](char* buf, int k0) {
        gl_lds16(A + aO0 + k0, buf + d0);
        gl_lds16(A + aO1 + k0, buf + d1);
        gl_lds16(A + aO0 + 1024 + k0, buf + 8192 + d0);
        gl_lds16(A + aO1 + 1024 + k0, buf + 8192 + d1);
        gl_lds16(Bp + bO0 + k0, buf + 16384 + d0);
        gl_lds16(Bp + bO1 + k0, buf + 16384 + d1);
    };

    // prologue: chunks 0,1,2 into bufs 0,1,2
    stage(smem, 0);
    stage(smem + 24576, 64);
    stage(smem + 49152, 128);

    char* p0 = smem;
    char* p1 = smem + 24576;
    char* p2 = smem + 49152;
    char* p3 = smem + 73728;

    for (int c = 0; c < 16; ++c) {
        // wait: oldest in-flight chunk (c) has landed in LDS (per-wave), then
        // barrier makes ALL waves' chunk-c DMA visible + finishes buf-reuse reads.
        if (c < 14)      asm volatile("s_waitcnt vmcnt(12)" ::: "memory");
        else if (c == 14) asm volatile("s_waitcnt vmcnt(6)" ::: "memory");
        else              asm volatile("s_waitcnt vmcnt(0)" ::: "memory");
        __builtin_amdgcn_s_barrier();
        if (c < 13) stage(p3, (c + 3) * 64);   // overwrite buf consumed at c-1
        __builtin_amdgcn_sched_barrier(0);

        const u16* sAhi = (const u16*)p0;
        const u16* sAlo = (const u16*)(p0 + 8192);
        const u16* sB   = (const u16*)(p0 + 16384);

#pragma unroll
        for (int kf = 0; kf < 2; ++kf) {
            const int cu = kf * 4 + q;
            bf16x8 b0 = lds_read_sw(sB, wn + fm, cu);
            bf16x8 b1 = lds_read_sw(sB, wn + 16 + fm, cu);
            bf16x8 ah0 = lds_read_sw(sAhi, wm + fm, cu);
            bf16x8 ah1 = lds_read_sw(sAhi, wm + 16 + fm, cu);
            bf16x8 al0 = lds_read_sw(sAlo, wm + fm, cu);
            bf16x8 al1 = lds_read_sw(sAlo, wm + 16 + fm, cu);
            acc[0][0] = __builtin_amdgcn_mfma_f32_16x16x32_bf16(ah0, b0, acc[0][0], 0, 0, 0);
            acc[0][1] = __builtin_amdgcn_mfma_f32_16x16x32_bf16(ah0, b1, acc[0][1], 0, 0, 0);
            acc[1][0] = __builtin_amdgcn_mfma_f32_16x16x32_bf16(ah1, b0, acc[1][0], 0, 0, 0);
            acc[1][1] = __builtin_amdgcn_mfma_f32_16x16x32_bf16(ah1, b1, acc[1][1], 0, 0, 0);
            acc[0][0] = __builtin_amdgcn_mfma_f32_16x16x32_bf16(al0, b0, acc[0][0], 0, 0, 0);
            acc[0][1] = __builtin_amdgcn_mfma_f32_16x16x32_bf16(al0, b1, acc[0][1], 0, 0, 0);
            acc[1][0] = __builtin_amdgcn_mfma_f32_16x16x32_bf16(al1, b0, acc[1][0], 0, 0, 0);
            acc[1][1] = __builtin_amdgcn_mfma_f32_16x16x32_bf16(al1, b1, acc[1][1], 0, 0, 0);
        }

        char* t = p0; p0 = p1; p1 = p2; p2 = p3; p3 = t;
    }

    __syncthreads();   // full drain before reusing smem as sG

    // Epilogue: acc -> sG (fp32 [64][68]) -> fused LSTM elementwise.
    float* sG = (float*)smem;
#pragma unroll
    for (int m = 0; m < 2; ++m)
#pragma unroll
        for (int n = 0; n < 2; ++n)
#pragma unroll
            for (int r = 0; r < 4; ++r) {
                int row = wm + m * 16 + q * 4 + r;
                int col = wn + n * 16 + fm;
                sG[row * 68 + col] = acc[m][n][r];
            }
    __syncthreads();

#pragma unroll
    for (int j = 0; j < 4; ++j) {
        int cell = tid + j * 256;           // 64 rows x 16 hcols
        int row = cell >> 4, hc = cell & 15;
        const float4 g4 = *(const float4*)&sG[row * 68 + hc * 4];
        const float4 b4 = *(const float4*)&bsumv[n0 + hc * 4];
        float gi = g4.x + b4.x, gf = g4.y + b4.y, gg = g4.z + b4.z, go = g4.w + b4.w;
        int grow = row0 + row;
        int ghc = (n0 >> 2) + hc;
        int cidx = grow * 512 + ghc;
        float c_old = cbuf[cidx];
        float is = sigmoid_fast(gi);
        float fs = sigmoid_fast(gf);
        float os = sigmoid_fast(go);
        float gt = tanh_fast(gg);
        float cn = fs * c_old + is * gt;
        float hn = os * tanh_fast(cn);
        cbuf[cidx] = cn;
        u16 hh = f2bf(hn);
        float hlo = hn - bf2f(hh);
        u16 hl = f2bf(hlo);
        size_t base1 = (size_t)grow * 2048 + hoff1;
        hdst1[base1 + ghc] = hh;
        hdst1[base1 + 1024 + ghc] = hl;
        if (!IS_L1) {
            size_t base2 = (size_t)grow * 2048 + hoff2;
            hdst2[base2 + ghc] = hh;
            hdst2[base2 + 1536 - 512 + ghc] = hl;   // +1024 past hoff2 base
        } else {
            size_t ab = (size_t)grow * 2048;
            float h0v = bf2f(h0src[ab + ghc]) + bf2f(h0src[ab + 1024 + ghc]);
            float hs = h0v + hn;
            u16 sh = f2bf(hs);
            float sl = hs - bf2f(sh);
            hsumdst[ab + ghc] = sh;
            hsumdst[ab + 1024 + ghc] = f2bf(sl);
            seqdst[(size_t)grow * 512 + ghc] = sh;
        }
    }
}

// ------------------------------------------------------------------- MLP -----
template <int RELU, int FINAL>
__global__ __launch_bounds__(256) void mlp_gemm(
    const u16* __restrict__ A, const u16* __restrict__ Bw, const float* __restrict__ bias,
    u16* __restrict__ ybf, float* __restrict__ yf32)
{
    __shared__ char smem[36864];
    u16* sA = (u16*)smem;             // [64][72]
    u16* sB = (u16*)(smem + 9216);    // [128][72]

    const int tid = threadIdx.x;
    const int lane = tid & 63, wid = tid >> 6;
    const int row0 = blockIdx.y * 64;
    const int n0 = blockIdx.x * 128;
    const int wn = wid * 32;
    const int fm = lane & 15;
    const int fkbase = (lane >> 4) * 8;

    f32x4 acc[4][2];
#pragma unroll
    for (int m = 0; m < 4; ++m) { acc[m][0] = (f32x4)0.f; acc[m][1] = (f32x4)0.f; }

    for (int kk = 0; kk < 8; ++kk) {
        const int k0 = kk * 64;
        __syncthreads();
#pragma unroll
        for (int r = 0; r < 2; ++r) {
            int c = tid + r * 256;
            int row = c >> 3, cc = (c & 7) * 8;
            *(bf16x8*)&sA[row * 72 + cc] = *(const bf16x8*)&A[(size_t)(row0 + row) * 512 + k0 + cc];
        }
#pragma unroll
        for (int r = 0; r < 4; ++r) {
            int c = tid + r * 256;
            int row = c >> 3, cc = (c & 7) * 8;
            *(bf16x8*)&sB[row * 72 + cc] = *(const bf16x8*)&Bw[(size_t)(n0 + row) * 512 + k0 + cc];
        }
        __syncthreads();
#pragma unroll
        for (int kf = 0; kf < 2; ++kf) {
            const int kb = kf * 32 + fkbase;
            bf16x8 b0 = *(const bf16x8*)&sB[(wn + fm) * 72 + kb];
            bf16x8 b1 = *(const bf16x8*)&sB[(wn + 16 + fm) * 72 + kb];
#pragma unroll
            for (int m = 0; m < 4; ++m) {
                bf16x8 ah = *(const bf16x8*)&sA[(m * 16 + fm) * 72 + kb];
                acc[m][0] = __builtin_amdgcn_mfma_f32_16x16x32_bf16(ah, b0, acc[m][0], 0, 0, 0);
                acc[m][1] = __builtin_amdgcn_mfma_f32_16x16x32_bf16(ah, b1, acc[m][1], 0, 0, 0);
            }
        }
    }

    __syncthreads();
    float* sG = (float*)smem;  // [64][132]
#pragma unroll
    for (int m = 0; m < 4; ++m)
#pragma unroll
        for (int n = 0; n < 2; ++n)
#pragma unroll
            for (int r = 0; r < 4; ++r) {
                int row = m * 16 + (lane >> 4) * 4 + r;
                int col = wn + n * 16 + fm;
                sG[row * 132 + col] = acc[m][n][r];
            }
    __syncthreads();

    const int row = tid >> 2;
    const int cg = (tid & 3) * 32;
    const size_t r = (size_t)row0 + row;
#pragma unroll
    for (int c = cg; c < cg + 32; c += 4) {
        float4 g = *(const float4*)&sG[row * 132 + c];
        float4 b = *(const float4*)&bias[n0 + c];
        float v0 = g.x + b.x, v1 = g.y + b.y, v2 = g.z + b.z, v3 = g.w + b.w;
        if (RELU) {
            v0 = fmaxf(v0, 0.f); v1 = fmaxf(v1, 0.f); v2 = fmaxf(v2, 0.f); v3 = fmaxf(v3, 0.f);
        }
        if (!FINAL) {
            ushort4 p;
            p.x = f2bf(v0); p.y = f2bf(v1); p.z = f2bf(v2); p.w = f2bf(v3);
            *(ushort4*)&ybf[r * 512 + n0 + c] = p;
        } else {
            int tt = (int)(r >> 9), bb = (int)(r & 511);  // seq row r = t*512 + b
            float4 o; o.x = v0; o.y = v1; o.z = v2; o.w = v3;
            *(float4*)&yf32[((size_t)bb * 128 + tt) * 512 + n0 + c] = o;
        }
    }
}

// ---------------------------------------------------------------- launch -----
extern "C" void kernel_launch(void* const* d_in, const int* in_sizes, int n_in,
                              void* d_out, int out_size, void* d_ws, size_t ws_size,
                              hipStream_t stream) {
    const float* x    = (const float*)d_in[0];
    const float* W_ih = (const float*)d_in[1];
    const float* W_hh = (const float*)d_in[2];
    const float* b_ih = (const float*)d_in[3];
    const float* b_hh = (const float*)d_in[4];
    const float* fc1w = (const float*)d_in[5];
    const float* fc1b = (const float*)d_in[6];
    const float* fc2w = (const float*)d_in[7];
    const float* fc2b = (const float*)d_in[8];
    const float* fc3w = (const float*)d_in[9];
    const float* fc3b = (const float*)d_in[10];

    char* ws = (char*)d_ws;
    u16* Bpack = (u16*)(ws);                          // 8,388,608 B
    u16* fcw   = (u16*)(ws + 8388608);                // 1,572,864 B
    float* bsum = (float*)(ws + 9961472);             // 16,384 B
    u16* A0[2] = { (u16*)(ws + 9977856), (u16*)(ws + 9977856 + 2097152) };
    u16* A1[2] = { (u16*)(ws + 14172160), (u16*)(ws + 14172160 + 2097152) };
    float* c0 = (float*)(ws + 18366464);
    float* c1 = (float*)(ws + 19415040);
    u16* seqb = (u16*)(ws + 20463616);                // 67,108,864 (reused as y2)
    u16* y1   = (u16*)(ws + 87572480);                // 67,108,864
    float* out = (float*)d_out;

    prepack<<<dim3(512), dim3(256), 0, stream>>>(W_ih, W_hh, b_ih, b_hh, fc1w, fc2w, fc3w,
                                                 Bpack, bsum, fcw);
    initbufs<<<dim3(512), dim3(256), 0, stream>>>(x, A0[0], A1[0], c0, c1);

    for (int t = 0; t < 128; ++t) {
        int cur = t & 1, nxt = cur ^ 1;
        lstm_step<0><<<dim3(256), dim3(256), 0, stream>>>(
            A0[cur], Bpack, bsum, c0,
            A1[cur], 0, A0[nxt], 512, nullptr, nullptr, nullptr);
        lstm_step<1><<<dim3(256), dim3(256), 0, stream>>>(
            A1[cur], Bpack + 2048 * 1024, bsum + 2048, c1,
            A1[nxt], 512, nullptr, 0, A1[cur], A0[nxt], seqb + (size_t)t * 512 * 512);
    }

    mlp_gemm<1, 0><<<dim3(4, 1024), dim3(256), 0, stream>>>(seqb, fcw, fc1b, y1, nullptr);
    mlp_gemm<1, 0><<<dim3(4, 1024), dim3(256), 0, stream>>>(y1, fcw + 512 * 512, fc2b, seqb, nullptr);
    mlp_gemm<0, 1><<<dim3(4, 1024), dim3(256), 0, stream>>>(seqb, fcw + 2 * 512 * 512, fc3b, nullptr, out);
}

// Round 5
// 2418.900 us; speedup vs baseline: 5.0055x; 1.2286x over previous
//
#include <hip/hip_runtime.h>
#include <cstdint>
#include <cstddef>

// DecoderLSTM: 2-layer LSTM (B=512,H=512,T=128) + 3-layer MLP head.
// bf16 MFMA; A-operand bf16 hi+lo (K doubled) for accuracy; fp32 cell state.
// Round 5: K-split pipelining. gates_s = X_s@Wx + H_s@Wh; the H-half is computed
// one dispatch EARLY (H ready a step before X) by 256 "partial" blocks while 256
// "completion" blocks finish the current step. 512 blocks = 2/CU → stalls overlap.
// Partials flow through a fragment-layout gbuf across kernel boundaries (coherent).

using u16 = unsigned short;
typedef __attribute__((ext_vector_type(8))) short bf16x8;
typedef __attribute__((ext_vector_type(4))) float f32x4;

__device__ __forceinline__ u16 f2bf(float f) {
    union { float f; uint32_t u; } v; v.f = f;
    uint32_t u = v.u;
    uint32_t r = (u + 0x7fffu + ((u >> 16) & 1u)) >> 16;
    return (u16)r;
}
__device__ __forceinline__ float bf2f(u16 h) {
    union { uint32_t u; float f; } v; v.u = ((uint32_t)h) << 16;
    return v.f;
}
__device__ __forceinline__ float tanh_fast(float v) {
    float a = fabsf(v);
    float t = __expf(-2.f * a);
    float r = (1.f - t) / (1.f + t);
    return copysignf(r, v);
}
__device__ __forceinline__ float sigmoid_fast(float v) {
    return 1.f / (1.f + __expf(-v));
}

__device__ __forceinline__ void gl_lds16(const u16* g, char* l) {
    __builtin_amdgcn_global_load_lds((const __attribute__((address_space(1))) char*)(const char*)g,
                                     (__attribute__((address_space(3))) char*)l, 16, 0, 0);
}

// Swizzled LDS read: tile [64 rows][64 bf16] linear (128B rows = 8 x 16B units),
// unit u' holds global col-unit u'^(row&7). Involution applied to global src on
// stage and to the read index here (both sides, rule #21).
__device__ __forceinline__ bf16x8 lds_read_sw(const u16* tile, int row, int cu) {
    int unit = (row << 3) | (cu ^ (row & 7));
    return *(const bf16x8*)&tile[unit << 3];
}

// ---------------------------------------------------------------- prepack ----
// Bpack[l][np][k], np = hcol*4 + gate (i,f,g,o), k: 0..511 = W_ih, 512..1023 = W_hh
__global__ __launch_bounds__(256) void prepack(
    const float* __restrict__ W_ih, const float* __restrict__ W_hh,
    const float* __restrict__ b_ih, const float* __restrict__ b_hh,
    const float* __restrict__ fc1w, const float* __restrict__ fc2w, const float* __restrict__ fc3w,
    u16* __restrict__ Bpack, float* __restrict__ bsumv, u16* __restrict__ fcw)
{
    int stride = gridDim.x * blockDim.x;
    int tid0 = blockIdx.x * blockDim.x + threadIdx.x;
    for (int idx = tid0; idx < 2 * 2048 * 1024; idx += stride) {
        int l = idx >> 21;
        int rem = idx & ((1 << 21) - 1);
        int np = rem >> 10;
        int k = rem & 1023;
        int n = (np & 3) * 512 + (np >> 2);
        float v = (k < 512) ? W_ih[((size_t)l * 2048 + n) * 512 + k]
                            : W_hh[((size_t)l * 2048 + n) * 512 + (k - 512)];
        Bpack[idx] = f2bf(v);
    }
    for (int idx = tid0; idx < 2 * 2048; idx += stride) {
        int l = idx >> 11;
        int np = idx & 2047;
        int n = (np & 3) * 512 + (np >> 2);
        bsumv[idx] = b_ih[l * 2048 + n] + b_hh[l * 2048 + n];
    }
    for (int idx = tid0; idx < 3 * 512 * 512; idx += stride) {
        const float* w = idx < 262144 ? fc1w : (idx < 524288 ? fc2w : fc3w);
        fcw[idx] = f2bf(w[idx & 262143]);
    }
}

// A buffers: [512][2048] bf16: [0:512)=X hi, [512:1024)=h hi, [1024:1536)=X lo, [1536:2048)=h lo
__global__ __launch_bounds__(256) void initbufs(
    const float* __restrict__ x, u16* __restrict__ A0_0, u16* __restrict__ A1_0,
    float* __restrict__ c0, float* __restrict__ c1, float* __restrict__ gb0)
{
    int stride = gridDim.x * blockDim.x;
    int tid0 = blockIdx.x * blockDim.x + threadIdx.x;
    for (int idx = tid0; idx < 512 * 512; idx += stride) {
        int row = idx >> 9, col = idx & 511;
        float xv = x[idx];
        u16 hi = f2bf(xv);
        float lo = xv - bf2f(hi);
        size_t b = (size_t)row * 2048;
        A0_0[b + col] = hi;
        A0_0[b + 1024 + col] = f2bf(lo);
        A1_0[b + 512 + col] = 0;
        A1_0[b + 1536 + col] = 0;
        c0[idx] = 0.f;
        c1[idx] = 0.f;
    }
    for (int idx = tid0; idx < 1048576; idx += stride) gb0[idx] = 0.f;  // partial0(0) = 0
}

// --------------------------------------------------------------- lstm phase --
// 512 blocks x 256 thr (2/CU). Blocks 0..255: completion (gates = gbufR + X@W_x,
// epilogue). Blocks 256..511: partial for NEXT sub-step (gbufW = H@W_h).
// Each role: 64 rows x 64 n'-cols, 8 chunks of 64k (hi+lo), depth-2 vmcnt pipeline,
// 3 LDS bufs x 24KB = 72KB (2 blocks/CU fit in 160KB).
template <int IS_L1>
__global__ __launch_bounds__(256) void lstm_phase(
    const u16* __restrict__ Ax, const u16* __restrict__ Ah, int hoffH,
    const u16* __restrict__ Wc, const u16* __restrict__ Wp,
    const float* __restrict__ gbufR, float* __restrict__ gbufW,
    const float* __restrict__ bsumv, float* __restrict__ cbuf,
    u16* __restrict__ hdst, const u16* __restrict__ h0src,
    u16* __restrict__ hsumdst, u16* __restrict__ seqdst)
{
    __shared__ char smem[73728];   // 3 bufs x (Ahi 8K | Alo 8K | W 8K)

    const int id = blockIdx.x;
    const bool isPartial = id >= 256;
    const int rid = id & 255;
    const int xcd = rid & 7, slot = rid >> 3;
    const int nb = xcd * 4 + (slot & 3);   // 0..31
    const int rg = slot >> 2;              // 0..7
    const int n0 = nb * 64;
    const int row0 = rg * 64;
    const int tile = rg * 32 + nb;

    const u16* Abase = isPartial ? Ah : Ax;
    const int xoff = isPartial ? hoffH : 0;
    const u16* Wbase = isPartial ? Wp : Wc;

    const int tid = threadIdx.x;
    const int lane = tid & 63, wid = tid >> 6;
    const int wm = (wid >> 1) * 32, wn = (wid & 1) * 32;
    const int fm = lane & 15, q = lane >> 4;

    // staging: wave w stages 16B-units [w*128, w*128+128); global src pre-swizzled
    const int s0 = wid * 128 + lane, s1 = s0 + 64;
    const int r0s = s0 >> 3, c0s = ((s0 & 7) ^ (r0s & 7)) << 3;
    const int r1s = s1 >> 3, c1s = ((s1 & 7) ^ (r1s & 7)) << 3;
    const size_t aO0 = (size_t)(row0 + r0s) * 2048 + xoff + c0s;
    const size_t aO1 = (size_t)(row0 + r1s) * 2048 + xoff + c1s;
    const size_t bO0 = (size_t)(n0 + r0s) * 1024 + c0s;
    const size_t bO1 = (size_t)(n0 + r1s) * 1024 + c1s;
    const int d0 = wid * 2048, d1 = d0 + 1024;

    f32x4 acc[2][2];
    acc[0][0] = (f32x4)0.f; acc[0][1] = (f32x4)0.f;
    acc[1][0] = (f32x4)0.f; acc[1][1] = (f32x4)0.f;

    auto stage = [&](char* buf, int k0) {
        gl_lds16(Abase + aO0 + k0, buf + d0);
        gl_lds16(Abase + aO1 + k0, buf + d1);
        gl_lds16(Abase + aO0 + 1024 + k0, buf + 8192 + d0);
        gl_lds16(Abase + aO1 + 1024 + k0, buf + 8192 + d1);
        gl_lds16(Wbase + bO0 + k0, buf + 16384 + d0);
        gl_lds16(Wbase + bO1 + k0, buf + 16384 + d1);
    };

    char* p0 = smem;
    char* p1 = smem + 24576;
    char* p2 = smem + 49152;

    stage(p0, 0);
    stage(p1, 64);

    for (int c = 0; c < 8; ++c) {
        if (c < 7) asm volatile("s_waitcnt vmcnt(6)" ::: "memory");
        else       asm volatile("s_waitcnt vmcnt(0)" ::: "memory");
        __builtin_amdgcn_s_barrier();
        if (c < 6) stage(p2, (c + 2) * 64);   // overwrites buf consumed at c-1
        __builtin_amdgcn_sched_barrier(0);

        const u16* sAhi = (const u16*)p0;
        const u16* sAlo = (const u16*)(p0 + 8192);
        const u16* sB   = (const u16*)(p0 + 16384);

#pragma unroll
        for (int kf = 0; kf < 2; ++kf) {
            const int cu = kf * 4 + q;
            bf16x8 b0 = lds_read_sw(sB, wn + fm, cu);
            bf16x8 b1 = lds_read_sw(sB, wn + 16 + fm, cu);
            bf16x8 ah0 = lds_read_sw(sAhi, wm + fm, cu);
            bf16x8 ah1 = lds_read_sw(sAhi, wm + 16 + fm, cu);
            bf16x8 al0 = lds_read_sw(sAlo, wm + fm, cu);
            bf16x8 al1 = lds_read_sw(sAlo, wm + 16 + fm, cu);
            acc[0][0] = __builtin_amdgcn_mfma_f32_16x16x32_bf16(ah0, b0, acc[0][0], 0, 0, 0);
            acc[0][1] = __builtin_amdgcn_mfma_f32_16x16x32_bf16(ah0, b1, acc[0][1], 0, 0, 0);
            acc[1][0] = __builtin_amdgcn_mfma_f32_16x16x32_bf16(ah1, b0, acc[1][0], 0, 0, 0);
            acc[1][1] = __builtin_amdgcn_mfma_f32_16x16x32_bf16(ah1, b1, acc[1][1], 0, 0, 0);
            acc[0][0] = __builtin_amdgcn_mfma_f32_16x16x32_bf16(al0, b0, acc[0][0], 0, 0, 0);
            acc[0][1] = __builtin_amdgcn_mfma_f32_16x16x32_bf16(al0, b1, acc[0][1], 0, 0, 0);
            acc[1][0] = __builtin_amdgcn_mfma_f32_16x16x32_bf16(al1, b0, acc[1][0], 0, 0, 0);
            acc[1][1] = __builtin_amdgcn_mfma_f32_16x16x32_bf16(al1, b1, acc[1][1], 0, 0, 0);
        }

        char* t = p0; p0 = p1; p1 = p2; p2 = t;
    }

    // ---------------- partial role: dump fragments to gbufW, done --------------
    if (isPartial) {
        float* dst = gbufW + (size_t)tile * 4096 + wid * 1024 + lane * 4;
        *(f32x4*)(dst +   0) = acc[0][0];
        *(f32x4*)(dst + 256) = acc[0][1];
        *(f32x4*)(dst + 512) = acc[1][0];
        *(f32x4*)(dst + 768) = acc[1][1];
        return;
    }

    // ---------------- completion role: add partial, LSTM epilogue --------------
    {
        const float* src = gbufR + (size_t)tile * 4096 + wid * 1024 + lane * 4;
        acc[0][0] += *(const f32x4*)(src +   0);
        acc[0][1] += *(const f32x4*)(src + 256);
        acc[1][0] += *(const f32x4*)(src + 512);
        acc[1][1] += *(const f32x4*)(src + 768);
    }

    __syncthreads();   // drain before reusing smem as sG
    float* sG = (float*)smem;  // [64][68]
#pragma unroll
    for (int m = 0; m < 2; ++m)
#pragma unroll
        for (int n = 0; n < 2; ++n)
#pragma unroll
            for (int r = 0; r < 4; ++r) {
                int row = wm + m * 16 + q * 4 + r;
                int col = wn + n * 16 + fm;
                sG[row * 68 + col] = acc[m][n][r];
            }
    __syncthreads();

#pragma unroll
    for (int j = 0; j < 4; ++j) {
        int cell = tid + j * 256;           // 64 rows x 16 hcols
        int row = cell >> 4, hc = cell & 15;
        const float4 g4 = *(const float4*)&sG[row * 68 + hc * 4];
        const float4 b4 = *(const float4*)&bsumv[n0 + hc * 4];
        float gi = g4.x + b4.x, gf = g4.y + b4.y, gg = g4.z + b4.z, go = g4.w + b4.w;
        int grow = row0 + row;
        int ghc = (n0 >> 2) + hc;
        int cidx = grow * 512 + ghc;
        float c_old = cbuf[cidx];
        float is = sigmoid_fast(gi);
        float fs = sigmoid_fast(gf);
        float os = sigmoid_fast(go);
        float gt = tanh_fast(gg);
        float cn = fs * c_old + is * gt;
        float hn = os * tanh_fast(cn);
        cbuf[cidx] = cn;
        u16 hh = f2bf(hn);
        float hlo = hn - bf2f(hh);
        u16 hl = f2bf(hlo);
        size_t ab = (size_t)grow * 2048;
        if (!IS_L1) {
            // h0(t) -> X-slot of A1[cur] (read by layer1 completion AND partial0(t+1))
            hdst[ab + ghc] = hh;
            hdst[ab + 1024 + ghc] = hl;
        } else {
            // h1(t) -> h-slot of A1[nxt] (read by partial1(t+1))
            hdst[ab + 512 + ghc] = hh;
            hdst[ab + 1536 + ghc] = hl;
            // hsum(t) = h0(t) + h1(t) -> X-slot of A0[nxt] + seq output
            float h0v = bf2f(h0src[ab + ghc]) + bf2f(h0src[ab + 1024 + ghc]);
            float hs = h0v + hn;
            u16 sh = f2bf(hs);
            float sl = hs - bf2f(sh);
            hsumdst[ab + ghc] = sh;
            hsumdst[ab + 1024 + ghc] = f2bf(sl);
            seqdst[(size_t)grow * 512 + ghc] = sh;
        }
    }
}

// ------------------------------------------------------------------- MLP -----
template <int RELU, int FINAL>
__global__ __launch_bounds__(256) void mlp_gemm(
    const u16* __restrict__ A, const u16* __restrict__ Bw, const float* __restrict__ bias,
    u16* __restrict__ ybf, float* __restrict__ yf32)
{
    __shared__ char smem[36864];
    u16* sA = (u16*)smem;             // [64][72]
    u16* sB = (u16*)(smem + 9216);    // [128][72]

    const int tid = threadIdx.x;
    const int lane = tid & 63, wid = tid >> 6;
    const int row0 = blockIdx.y * 64;
    const int n0 = blockIdx.x * 128;
    const int wn = wid * 32;
    const int fm = lane & 15;
    const int fkbase = (lane >> 4) * 8;

    f32x4 acc[4][2];
#pragma unroll
    for (int m = 0; m < 4; ++m) { acc[m][0] = (f32x4)0.f; acc[m][1] = (f32x4)0.f; }

    for (int kk = 0; kk < 8; ++kk) {
        const int k0 = kk * 64;
        __syncthreads();
#pragma unroll
        for (int r = 0; r < 2; ++r) {
            int c = tid + r * 256;
            int row = c >> 3, cc = (c & 7) * 8;
            *(bf16x8*)&sA[row * 72 + cc] = *(const bf16x8*)&A[(size_t)(row0 + row) * 512 + k0 + cc];
        }
#pragma unroll
        for (int r = 0; r < 4; ++r) {
            int c = tid + r * 256;
            int row = c >> 3, cc = (c & 7) * 8;
            *(bf16x8*)&sB[row * 72 + cc] = *(const bf16x8*)&Bw[(size_t)(n0 + row) * 512 + k0 + cc];
        }
        __syncthreads();
#pragma unroll
        for (int kf = 0; kf < 2; ++kf) {
            const int kb = kf * 32 + fkbase;
            bf16x8 b0 = *(const bf16x8*)&sB[(wn + fm) * 72 + kb];
            bf16x8 b1 = *(const bf16x8*)&sB[(wn + 16 + fm) * 72 + kb];
#pragma unroll
            for (int m = 0; m < 4; ++m) {
                bf16x8 ah = *(const bf16x8*)&sA[(m * 16 + fm) * 72 + kb];
                acc[m][0] = __builtin_amdgcn_mfma_f32_16x16x32_bf16(ah, b0, acc[m][0], 0, 0, 0);
                acc[m][1] = __builtin_amdgcn_mfma_f32_16x16x32_bf16(ah, b1, acc[m][1], 0, 0, 0);
            }
        }
    }

    __syncthreads();
    float* sG = (float*)smem;  // [64][132]
#pragma unroll
    for (int m = 0; m < 4; ++m)
#pragma unroll
        for (int n = 0; n < 2; ++n)
#pragma unroll
            for (int r = 0; r < 4; ++r) {
                int row = m * 16 + (lane >> 4) * 4 + r;
                int col = wn + n * 16 + fm;
                sG[row * 132 + col] = acc[m][n][r];
            }
    __syncthreads();

    const int row = tid >> 2;
    const int cg = (tid & 3) * 32;
    const size_t r = (size_t)row0 + row;
#pragma unroll
    for (int c = cg; c < cg + 32; c += 4) {
        float4 g = *(const float4*)&sG[row * 132 + c];
        float4 b = *(const float4*)&bias[n0 + c];
        float v0 = g.x + b.x, v1 = g.y + b.y, v2 = g.z + b.z, v3 = g.w + b.w;
        if (RELU) {
            v0 = fmaxf(v0, 0.f); v1 = fmaxf(v1, 0.f); v2 = fmaxf(v2, 0.f); v3 = fmaxf(v3, 0.f);
        }
        if (!FINAL) {
            ushort4 p;
            p.x = f2bf(v0); p.y = f2bf(v1); p.z = f2bf(v2); p.w = f2bf(v3);
            *(ushort4*)&ybf[r * 512 + n0 + c] = p;
        } else {
            int tt = (int)(r >> 9), bb = (int)(r & 511);  // seq row r = t*512 + b
            float4 o; o.x = v0; o.y = v1; o.z = v2; o.w = v3;
            *(float4*)&yf32[((size_t)bb * 128 + tt) * 512 + n0 + c] = o;
        }
    }
}

// ---------------------------------------------------------------- launch -----
extern "C" void kernel_launch(void* const* d_in, const int* in_sizes, int n_in,
                              void* d_out, int out_size, void* d_ws, size_t ws_size,
                              hipStream_t stream) {
    const float* x    = (const float*)d_in[0];
    const float* W_ih = (const float*)d_in[1];
    const float* W_hh = (const float*)d_in[2];
    const float* b_ih = (const float*)d_in[3];
    const float* b_hh = (const float*)d_in[4];
    const float* fc1w = (const float*)d_in[5];
    const float* fc1b = (const float*)d_in[6];
    const float* fc2w = (const float*)d_in[7];
    const float* fc2b = (const float*)d_in[8];
    const float* fc3w = (const float*)d_in[9];
    const float* fc3b = (const float*)d_in[10];

    char* ws = (char*)d_ws;
    u16* Bpack = (u16*)(ws);                          // 8,388,608 B
    u16* fcw   = (u16*)(ws + 8388608);                // 1,572,864 B
    float* bsum = (float*)(ws + 9961472);             // 16,384 B
    u16* A0[2] = { (u16*)(ws + 9977856), (u16*)(ws + 9977856 + 2097152) };
    u16* A1[2] = { (u16*)(ws + 14172160), (u16*)(ws + 14172160 + 2097152) };
    float* c0 = (float*)(ws + 18366464);
    float* c1 = (float*)(ws + 19415040);
    u16* seqb = (u16*)(ws + 20463616);                // 67,108,864 (reused as y2)
    u16* y1   = (u16*)(ws + 87572480);                // 67,108,864 (gbufs alias head)
    float* gb[2] = { (float*)(ws + 87572480), (float*)(ws + 87572480 + 4194304) };
    float* out = (float*)d_out;

    prepack<<<dim3(512), dim3(256), 0, stream>>>(W_ih, W_hh, b_ih, b_hh, fc1w, fc2w, fc3w,
                                                 Bpack, bsum, fcw);
    initbufs<<<dim3(512), dim3(256), 0, stream>>>(x, A0[0], A1[0], c0, c1, gb[0]);

    const int LSTR = 2048 * 1024;
    for (int s = 0; s < 256; ++s) {
        int t = s >> 1, layer = s & 1, cur = t & 1, nxt = cur ^ 1;
        float* gR = gb[s & 1];
        float* gW = gb[(s + 1) & 1];
        if (!layer) {
            // completion: gates0(t) = gR + hsum(t-1)@Wih0 -> h0(t) into A1[cur] X-slot
            // partial:    gW = h1(t-1)@Whh1   (h from A1[cur] h-slot, W = layer1 k[512:1024))
            lstm_phase<0><<<dim3(512), dim3(256), 0, stream>>>(
                A0[cur], A1[cur], 512, Bpack, Bpack + LSTR + 512,
                gR, gW, bsum, c0,
                A1[cur], nullptr, nullptr, nullptr);
        } else {
            // completion: gates1(t) = gR + h0(t)@Wih1 -> h1(t) into A1[nxt] h-slot, hsum -> A0[nxt]
            // partial:    gW = h0(t)@Whh0     (h0 from A1[cur] X-slot, W = layer0 k[512:1024))
            lstm_phase<1><<<dim3(512), dim3(256), 0, stream>>>(
                A1[cur], A1[cur], 0, Bpack + LSTR, Bpack + 512,
                gR, gW, bsum + 2048, c1,
                A1[nxt], A1[cur], A0[nxt], seqb + (size_t)t * 262144);
        }
    }

    mlp_gemm<1, 0><<<dim3(4, 1024), dim3(256), 0, stream>>>(seqb, fcw, fc1b, y1, nullptr);
    mlp_gemm<1, 0><<<dim3(4, 1024), dim3(256), 0, stream>>>(y1, fcw + 512 * 512, fc2b, seqb, nullptr);
    mlp_gemm<0, 1><<<dim3(4, 1024), dim3(256), 0, stream>>>(seqb, fcw + 2 * 512 * 512, fc3b, nullptr, out);
}

// Round 6
// 2022.596 us; speedup vs baseline: 5.9862x; 1.1959x over previous
//
#include <hip/hip_runtime.h>
#include <cstdint>
#include <cstddef>

// DecoderLSTM: 2-layer LSTM (B=512,H=512,T=128) + 3-layer MLP head.
// Round 6: full fp16 datapath (was bf16 + hi/lo A-compensation). fp16 gives
// 2^-11 rel error on BOTH operands vs {exact-A, 2^-8 bf16-W} before — strictly
// tighter — and halves staged A bytes, MFMA count, and LDS reads. fp32 cell
// state in registers; fp32 accumulators; fc3 output written fp32.
// Structure (proven round 5): K-split pipelining — gates_s = X_s@Wx + H_s@Wh;
// H-half computed one dispatch early by 256 partial blocks while 256 completion
// blocks finish the current step; 512 blocks = 2/CU; depth-2 counted-vmcnt
// pipeline with swizzled global_load_lds staging.

using u16 = unsigned short;
typedef __attribute__((ext_vector_type(8))) _Float16 f16x8;
typedef __attribute__((ext_vector_type(4))) float f32x4;

__device__ __forceinline__ u16 f2h(float f) {
    union { _Float16 h; u16 u; } v; v.h = (_Float16)f; return v.u;
}
__device__ __forceinline__ float h2f(u16 u) {
    union { u16 u; _Float16 h; } v; v.u = u; return (float)v.h;
}
__device__ __forceinline__ float tanh_fast(float v) {
    float a = fabsf(v);
    float t = __expf(-2.f * a);
    float r = (1.f - t) / (1.f + t);
    return copysignf(r, v);
}
__device__ __forceinline__ float sigmoid_fast(float v) {
    return 1.f / (1.f + __expf(-v));
}

__device__ __forceinline__ void gl_lds16(const u16* g, char* l) {
    __builtin_amdgcn_global_load_lds((const __attribute__((address_space(1))) char*)(const char*)g,
                                     (__attribute__((address_space(3))) char*)l, 16, 0, 0);
}

// Swizzled LDS read: tile [64 rows][64 f16] linear (128B rows = 8 x 16B units),
// unit u' holds global col-unit u'^(row&7). Involution applied to global src on
// stage and to the read index here (both sides, rule #21).
__device__ __forceinline__ f16x8 lds_read_sw(const u16* tile, int row, int cu) {
    int unit = (row << 3) | (cu ^ (row & 7));
    return *(const f16x8*)&tile[unit << 3];
}

// ---------------------------------------------------------------- prepack ----
// Bpack[l][np][k] (f16), np = hcol*4 + gate (i,f,g,o), k: 0..511 = W_ih, 512..1023 = W_hh
__global__ __launch_bounds__(256) void prepack(
    const float* __restrict__ W_ih, const float* __restrict__ W_hh,
    const float* __restrict__ b_ih, const float* __restrict__ b_hh,
    const float* __restrict__ fc1w, const float* __restrict__ fc2w, const float* __restrict__ fc3w,
    u16* __restrict__ Bpack, float* __restrict__ bsumv, u16* __restrict__ fcw)
{
    int stride = gridDim.x * blockDim.x;
    int tid0 = blockIdx.x * blockDim.x + threadIdx.x;
    for (int idx = tid0; idx < 2 * 2048 * 1024; idx += stride) {
        int l = idx >> 21;
        int rem = idx & ((1 << 21) - 1);
        int np = rem >> 10;
        int k = rem & 1023;
        int n = (np & 3) * 512 + (np >> 2);
        float v = (k < 512) ? W_ih[((size_t)l * 2048 + n) * 512 + k]
                            : W_hh[((size_t)l * 2048 + n) * 512 + (k - 512)];
        Bpack[idx] = f2h(v);
    }
    for (int idx = tid0; idx < 2 * 2048; idx += stride) {
        int l = idx >> 11;
        int np = idx & 2047;
        int n = (np & 3) * 512 + (np >> 2);
        bsumv[idx] = b_ih[l * 2048 + n] + b_hh[l * 2048 + n];
    }
    for (int idx = tid0; idx < 3 * 512 * 512; idx += stride) {
        const float* w = idx < 262144 ? fc1w : (idx < 524288 ? fc2w : fc3w);
        fcw[idx] = f2h(w[idx & 262143]);
    }
}

// A buffers: [512][1024] f16: cols [0:512) = X (x / hsum / h0-as-X), [512:1024) = h
__global__ __launch_bounds__(256) void initbufs(
    const float* __restrict__ x, u16* __restrict__ A0_0, u16* __restrict__ A1_0,
    float* __restrict__ c0, float* __restrict__ c1, float* __restrict__ gb0)
{
    int stride = gridDim.x * blockDim.x;
    int tid0 = blockIdx.x * blockDim.x + threadIdx.x;
    for (int idx = tid0; idx < 512 * 512; idx += stride) {
        int row = idx >> 9, col = idx & 511;
        size_t b = (size_t)row * 1024;
        A0_0[b + col] = f2h(x[idx]);
        A1_0[b + 512 + col] = 0;     // h1(-1) = 0
        c0[idx] = 0.f;
        c1[idx] = 0.f;
    }
    for (int idx = tid0; idx < 1048576; idx += stride) gb0[idx] = 0.f;  // H-half of step 0
}

// --------------------------------------------------------------- lstm phase --
// 512 blocks x 256 thr (2/CU). Blocks 0..255: completion (gates = gbufR + X@W_x,
// epilogue). Blocks 256..511: partial for NEXT sub-step (gbufW = H@W_h).
// Each role: 64 rows x 64 n'-cols, K=512 in 8 chunks of 64; depth-2 vmcnt pipeline,
// 3 LDS bufs x 16KB (A 8K | W 8K) = 48KB.
template <int IS_L1>
__global__ __launch_bounds__(256) void lstm_phase(
    const u16* __restrict__ Ax, const u16* __restrict__ Ah, int hoffH,
    const u16* __restrict__ Wc, const u16* __restrict__ Wp,
    const float* __restrict__ gbufR, float* __restrict__ gbufW,
    const float* __restrict__ bsumv, float* __restrict__ cbuf,
    u16* __restrict__ hdst, const u16* __restrict__ h0src,
    u16* __restrict__ hsumdst, u16* __restrict__ seqdst)
{
    __shared__ char smem[49152];   // 3 bufs x (A 8K | W 8K)

    const int id = blockIdx.x;
    const bool isPartial = id >= 256;
    const int rid = id & 255;
    const int xcd = rid & 7, slot = rid >> 3;
    const int nb = xcd * 4 + (slot & 3);   // 0..31
    const int rg = slot >> 2;              // 0..7
    const int n0 = nb * 64;
    const int row0 = rg * 64;
    const int tile = rg * 32 + nb;

    const u16* Abase = isPartial ? Ah : Ax;
    const int xoff = isPartial ? hoffH : 0;
    const u16* Wbase = isPartial ? Wp : Wc;

    const int tid = threadIdx.x;
    const int lane = tid & 63, wid = tid >> 6;
    const int wm = (wid >> 1) * 32, wn = (wid & 1) * 32;
    const int fm = lane & 15, q = lane >> 4;

    // staging: wave w stages 16B-units [w*128, w*128+128) of each 512-unit tile
    const int s0 = wid * 128 + lane, s1 = s0 + 64;
    const int r0s = s0 >> 3, c0s = ((s0 & 7) ^ (r0s & 7)) << 3;
    const int r1s = s1 >> 3, c1s = ((s1 & 7) ^ (r1s & 7)) << 3;
    const size_t aO0 = (size_t)(row0 + r0s) * 1024 + xoff + c0s;
    const size_t aO1 = (size_t)(row0 + r1s) * 1024 + xoff + c1s;
    const size_t bO0 = (size_t)(n0 + r0s) * 1024 + c0s;
    const size_t bO1 = (size_t)(n0 + r1s) * 1024 + c1s;
    const int d0 = wid * 2048, d1 = d0 + 1024;

    f32x4 acc[2][2];
    acc[0][0] = (f32x4)0.f; acc[0][1] = (f32x4)0.f;
    acc[1][0] = (f32x4)0.f; acc[1][1] = (f32x4)0.f;

    auto stage = [&](char* buf, int k0) {
        gl_lds16(Abase + aO0 + k0, buf + d0);
        gl_lds16(Abase + aO1 + k0, buf + d1);
        gl_lds16(Wbase + bO0 + k0, buf + 8192 + d0);
        gl_lds16(Wbase + bO1 + k0, buf + 8192 + d1);
    };

    char* p0 = smem;
    char* p1 = smem + 16384;
    char* p2 = smem + 32768;

    stage(p0, 0);
    stage(p1, 64);

    for (int c = 0; c < 8; ++c) {
        if (c < 7) asm volatile("s_waitcnt vmcnt(4)" ::: "memory");
        else       asm volatile("s_waitcnt vmcnt(0)" ::: "memory");
        __builtin_amdgcn_s_barrier();
        if (c < 6) stage(p2, (c + 2) * 64);   // overwrites buf consumed at c-1
        __builtin_amdgcn_sched_barrier(0);

        const u16* sA = (const u16*)p0;
        const u16* sB = (const u16*)(p0 + 8192);

#pragma unroll
        for (int kf = 0; kf < 2; ++kf) {
            const int cu = kf * 4 + q;
            f16x8 b0 = lds_read_sw(sB, wn + fm, cu);
            f16x8 b1 = lds_read_sw(sB, wn + 16 + fm, cu);
            f16x8 a0 = lds_read_sw(sA, wm + fm, cu);
            f16x8 a1 = lds_read_sw(sA, wm + 16 + fm, cu);
            acc[0][0] = __builtin_amdgcn_mfma_f32_16x16x32_f16(a0, b0, acc[0][0], 0, 0, 0);
            acc[0][1] = __builtin_amdgcn_mfma_f32_16x16x32_f16(a0, b1, acc[0][1], 0, 0, 0);
            acc[1][0] = __builtin_amdgcn_mfma_f32_16x16x32_f16(a1, b0, acc[1][0], 0, 0, 0);
            acc[1][1] = __builtin_amdgcn_mfma_f32_16x16x32_f16(a1, b1, acc[1][1], 0, 0, 0);
        }

        char* t = p0; p0 = p1; p1 = p2; p2 = t;
    }

    // ---------------- partial role: dump fragments to gbufW, done --------------
    if (isPartial) {
        float* dst = gbufW + (size_t)tile * 4096 + wid * 1024 + lane * 4;
        *(f32x4*)(dst +   0) = acc[0][0];
        *(f32x4*)(dst + 256) = acc[0][1];
        *(f32x4*)(dst + 512) = acc[1][0];
        *(f32x4*)(dst + 768) = acc[1][1];
        return;
    }

    // ---------------- completion role: add partial, LSTM epilogue --------------
    {
        const float* src = gbufR + (size_t)tile * 4096 + wid * 1024 + lane * 4;
        acc[0][0] += *(const f32x4*)(src +   0);
        acc[0][1] += *(const f32x4*)(src + 256);
        acc[1][0] += *(const f32x4*)(src + 512);
        acc[1][1] += *(const f32x4*)(src + 768);
    }

    __syncthreads();   // drain before reusing smem as sG
    float* sG = (float*)smem;  // [64][68]
#pragma unroll
    for (int m = 0; m < 2; ++m)
#pragma unroll
        for (int n = 0; n < 2; ++n)
#pragma unroll
            for (int r = 0; r < 4; ++r) {
                int row = wm + m * 16 + q * 4 + r;
                int col = wn + n * 16 + fm;
                sG[row * 68 + col] = acc[m][n][r];
            }
    __syncthreads();

#pragma unroll
    for (int j = 0; j < 4; ++j) {
        int cell = tid + j * 256;           // 64 rows x 16 hcols
        int row = cell >> 4, hc = cell & 15;
        const float4 g4 = *(const float4*)&sG[row * 68 + hc * 4];
        const float4 b4 = *(const float4*)&bsumv[n0 + hc * 4];
        float gi = g4.x + b4.x, gf = g4.y + b4.y, gg = g4.z + b4.z, go = g4.w + b4.w;
        int grow = row0 + row;
        int ghc = (n0 >> 2) + hc;
        int cidx = grow * 512 + ghc;
        float c_old = cbuf[cidx];
        float is = sigmoid_fast(gi);
        float fs = sigmoid_fast(gf);
        float os = sigmoid_fast(go);
        float gt = tanh_fast(gg);
        float cn = fs * c_old + is * gt;
        float hn = os * tanh_fast(cn);
        cbuf[cidx] = cn;
        u16 hh = f2h(hn);
        size_t ab = (size_t)grow * 1024;
        if (!IS_L1) {
            // h0(t) -> X-slot of A1[cur] (read by layer1 completion AND partial(s+1))
            hdst[ab + ghc] = hh;
        } else {
            // h1(t) -> h-slot of A1[nxt] (read by partial at s+1... s+2)
            hdst[ab + 512 + ghc] = hh;
            // hsum(t) = h0(t) + h1(t) -> X-slot of A0[nxt] + seq output
            float h0v = h2f(h0src[ab + ghc]);
            float hs = h0v + hn;
            hsumdst[ab + ghc] = f2h(hs);
            seqdst[(size_t)grow * 512 + ghc] = f2h(hs);
        }
    }
}

// ------------------------------------------------------------------- MLP -----
template <int RELU, int FINAL>
__global__ __launch_bounds__(256) void mlp_gemm(
    const u16* __restrict__ A, const u16* __restrict__ Bw, const float* __restrict__ bias,
    u16* __restrict__ yh, float* __restrict__ yf32)
{
    __shared__ char smem[36864];
    u16* sA = (u16*)smem;             // [64][72]
    u16* sB = (u16*)(smem + 9216);    // [128][72]

    const int tid = threadIdx.x;
    const int lane = tid & 63, wid = tid >> 6;
    const int row0 = blockIdx.y * 64;
    const int n0 = blockIdx.x * 128;
    const int wn = wid * 32;
    const int fm = lane & 15;
    const int fkbase = (lane >> 4) * 8;

    f32x4 acc[4][2];
#pragma unroll
    for (int m = 0; m < 4; ++m) { acc[m][0] = (f32x4)0.f; acc[m][1] = (f32x4)0.f; }

    for (int kk = 0; kk < 8; ++kk) {
        const int k0 = kk * 64;
        __syncthreads();
#pragma unroll
        for (int r = 0; r < 2; ++r) {
            int c = tid + r * 256;
            int row = c >> 3, cc = (c & 7) * 8;
            *(f16x8*)&sA[row * 72 + cc] = *(const f16x8*)&A[(size_t)(row0 + row) * 512 + k0 + cc];
        }
#pragma unroll
        for (int r = 0; r < 4; ++r) {
            int c = tid + r * 256;
            int row = c >> 3, cc = (c & 7) * 8;
            *(f16x8*)&sB[row * 72 + cc] = *(const f16x8*)&Bw[(size_t)(n0 + row) * 512 + k0 + cc];
        }
        __syncthreads();
#pragma unroll
        for (int kf = 0; kf < 2; ++kf) {
            const int kb = kf * 32 + fkbase;
            f16x8 b0 = *(const f16x8*)&sB[(wn + fm) * 72 + kb];
            f16x8 b1 = *(const f16x8*)&sB[(wn + 16 + fm) * 72 + kb];
#pragma unroll
            for (int m = 0; m < 4; ++m) {
                f16x8 ah = *(const f16x8*)&sA[(m * 16 + fm) * 72 + kb];
                acc[m][0] = __builtin_amdgcn_mfma_f32_16x16x32_f16(ah, b0, acc[m][0], 0, 0, 0);
                acc[m][1] = __builtin_amdgcn_mfma_f32_16x16x32_f16(ah, b1, acc[m][1], 0, 0, 0);
            }
        }
    }

    __syncthreads();
    float* sG = (float*)smem;  // [64][132]
#pragma unroll
    for (int m = 0; m < 4; ++m)
#pragma unroll
        for (int n = 0; n < 2; ++n)
#pragma unroll
            for (int r = 0; r < 4; ++r) {
                int row = m * 16 + (lane >> 4) * 4 + r;
                int col = wn + n * 16 + fm;
                sG[row * 132 + col] = acc[m][n][r];
            }
    __syncthreads();

    const int row = tid >> 2;
    const int cg = (tid & 3) * 32;
    const size_t r = (size_t)row0 + row;
#pragma unroll
    for (int c = cg; c < cg + 32; c += 4) {
        float4 g = *(const float4*)&sG[row * 132 + c];
        float4 b = *(const float4*)&bias[n0 + c];
        float v0 = g.x + b.x, v1 = g.y + b.y, v2 = g.z + b.z, v3 = g.w + b.w;
        if (RELU) {
            v0 = fmaxf(v0, 0.f); v1 = fmaxf(v1, 0.f); v2 = fmaxf(v2, 0.f); v3 = fmaxf(v3, 0.f);
        }
        if (!FINAL) {
            ushort4 p;
            p.x = f2h(v0); p.y = f2h(v1); p.z = f2h(v2); p.w = f2h(v3);
            *(ushort4*)&yh[r * 512 + n0 + c] = p;
        } else {
            int tt = (int)(r >> 9), bb = (int)(r & 511);  // seq row r = t*512 + b
            float4 o; o.x = v0; o.y = v1; o.z = v2; o.w = v3;
            *(float4*)&yf32[((size_t)bb * 128 + tt) * 512 + n0 + c] = o;
        }
    }
}

// ---------------------------------------------------------------- launch -----
extern "C" void kernel_launch(void* const* d_in, const int* in_sizes, int n_in,
                              void* d_out, int out_size, void* d_ws, size_t ws_size,
                              hipStream_t stream) {
    const float* x    = (const float*)d_in[0];
    const float* W_ih = (const float*)d_in[1];
    const float* W_hh = (const float*)d_in[2];
    const float* b_ih = (const float*)d_in[3];
    const float* b_hh = (const float*)d_in[4];
    const float* fc1w = (const float*)d_in[5];
    const float* fc1b = (const float*)d_in[6];
    const float* fc2w = (const float*)d_in[7];
    const float* fc2b = (const float*)d_in[8];
    const float* fc3w = (const float*)d_in[9];
    const float* fc3b = (const float*)d_in[10];

    char* ws = (char*)d_ws;
    u16* Bpack = (u16*)(ws);                          // 8,388,608 B
    u16* fcw   = (u16*)(ws + 8388608);                // 1,572,864 B
    float* bsum = (float*)(ws + 9961472);             // 16,384 B
    u16* A0[2] = { (u16*)(ws + 9977856),  (u16*)(ws + 11026432) };   // 1MB each
    u16* A1[2] = { (u16*)(ws + 12075008), (u16*)(ws + 13123584) };   // 1MB each
    float* c0 = (float*)(ws + 14172160);              // 1MB
    float* c1 = (float*)(ws + 15220736);              // 1MB
    u16* seqb = (u16*)(ws + 20463616);                // 67,108,864 (reused as y2)
    // gb (LSTM-era) aliases the y1 (MLP-era) region — disjoint lifetimes.
    float* gb[2] = { (float*)(ws + 87572480), (float*)(ws + 87572480 + 4194304) };
    u16* y1   = (u16*)(ws + 87572480);                // 67,108,864
    float* out = (float*)d_out;

    prepack<<<dim3(512), dim3(256), 0, stream>>>(W_ih, W_hh, b_ih, b_hh, fc1w, fc2w, fc3w,
                                                 Bpack, bsum, fcw);
    initbufs<<<dim3(512), dim3(256), 0, stream>>>(x, A0[0], A1[0], c0, c1, gb[0]);

    const int LSTR = 2048 * 1024;
    for (int s = 0; s < 256; ++s) {
        int t = s >> 1, layer = s & 1, cur = t & 1, nxt = cur ^ 1;
        float* gR = gb[s & 1];
        float* gW = gb[(s + 1) & 1];
        if (!layer) {
            // completion: gates0(t) = gR + hsum(t-1)@Wih0 -> h0(t) into A1[cur] X-slot
            // partial:    gW = h1(t-1)@Whh1   (h1 from A1[cur] h-slot, W = layer1 k[512:1024))
            lstm_phase<0><<<dim3(512), dim3(256), 0, stream>>>(
                A0[cur], A1[cur], 512, Bpack, Bpack + LSTR + 512,
                gR, gW, bsum, c0,
                A1[cur], nullptr, nullptr, nullptr);
        } else {
            // completion: gates1(t) = gR + h0(t)@Wih1 -> h1(t) into A1[nxt] h-slot, hsum -> A0[nxt]
            // partial:    gW = h0(t)@Whh0     (h0 from A1[cur] X-slot, W = layer0 k[512:1024))
            lstm_phase<1><<<dim3(512), dim3(256), 0, stream>>>(
                A1[cur], A1[cur], 0, Bpack + LSTR, Bpack + 512,
                gR, gW, bsum + 2048, c1,
                A1[nxt], A1[cur], A0[nxt], seqb + (size_t)t * 262144);
        }
    }

    mlp_gemm<1, 0><<<dim3(4, 1024), dim3(256), 0, stream>>>(seqb, fcw, fc1b, y1, nullptr);
    mlp_gemm<1, 0><<<dim3(4, 1024), dim3(256), 0, stream>>>(y1, fcw + 512 * 512, fc2b, seqb, nullptr);
    mlp_gemm<0, 1><<<dim3(4, 1024), dim3(256), 0, stream>>>(seqb, fcw + 2 * 512 * 512, fc3b, nullptr, out);
}